// Round 4
// baseline (13431.601 us; speedup 1.0000x reference)
//
#include <hip/hip_runtime.h>
#include <stdint.h>

#define LL 4
#define BATCH 128
#define TSEQ 1024
#define HID 512
#define G4 2048
#define NGRP 4    // pipelined kernel: batch groups (32 batches each)
#define BB 32     // batches per group (2 MFMA row-tiles)
#define KAP16 16  // hidden-slice WGs per group: 32 hidden cols (128 gate vals)
#define RING 8    // per-layer h ring depth (power of 2)

typedef __attribute__((ext_vector_type(8))) short s8v;   // 8 x bf16 fragment
typedef __attribute__((ext_vector_type(4))) float f4v;   // MFMA accumulator

__device__ __forceinline__ unsigned short f2bf(float f) {
  union { float f; unsigned u; } v; v.f = f;
  return (unsigned short)((v.u + 0x7fffu + ((v.u >> 16) & 1u)) >> 16);  // RNE
}

__device__ __forceinline__ float fsig(float x) { return 1.f / (1.f + __expf(-x)); }

__device__ __forceinline__ float ftanh(float x) {
  float a = __builtin_fabsf(x);
  float e = __expf(-2.f * a);
  float t = (1.f - e) / (1.f + e);
  return x < 0.f ? -t : t;
}

__global__ void cvt_f32_bf16(const float* __restrict__ in, unsigned short* __restrict__ out, int n4) {
  int stride = gridDim.x * blockDim.x;
  for (int i = blockIdx.x * blockDim.x + threadIdx.x; i < n4; i += stride) {
    f4v v = ((const f4v*)in)[i];
    union { unsigned short u[4]; unsigned long long d; } o;
    o.u[0] = f2bf(v.x); o.u[1] = f2bf(v.y); o.u[2] = f2bf(v.z); o.u[3] = f2bf(v.w);
    ((unsigned long long*)out)[i] = o.d;
  }
}

// Bounded flag spin with s_sleep backoff. Per-lane ptr/target; wave __all.
// Guard expiry -> wrong answer, never a hang.
__device__ __forceinline__ void pollv(const unsigned int* p, int idx, int tgt) {
  unsigned f = __hip_atomic_load(&p[idx], __ATOMIC_RELAXED, __HIP_MEMORY_SCOPE_AGENT);
  if (!__all((int)f >= tgt)) {
    for (int guard = 0; guard < (1 << 17); ++guard) {
      __builtin_amdgcn_s_sleep(1);
      f = __hip_atomic_load(&p[idx], __ATOMIC_RELAXED, __HIP_MEMORY_SCOPE_AGENT);
      if (__all((int)f >= tgt)) break;
    }
  }
  asm volatile("" ::: "memory");  // no compiler motion of data loads above the poll
}

// [32 rows x K=256] x [K=256 x 128 gate-cols] -> partial[32][128] in LDS.
// 2 row-tiles x 8 col-tiles x 8 K-frags = 128 MFMA.
// D layout (m89): col = lane&15, row = quad*4 + reg.
// Bank swizzle: phys col = col ^ (((row>>2)&3)<<4).
//   writer: row = bt*16+quad*4+r2 -> (row>>2)&3 = quad -> 4 quads hit 4
//     distinct 16-dword windows -> 64 lanes over 32 banks = 2-way (free).
//   reader: swz = ((bi>>2)&3)<<4 uniform over a wave's 2 rows; 32 consecutive
//     kk cover all banks -> 2-way (free). Same f(row) both sides.
template<bool ATOM>
__device__ __forceinline__ void gemm32x128(
    const unsigned short* __restrict__ base, size_t rstride,
    int bg0, int lm, int quad, int koffA,
    const s8v (&breg)[8][8], float (*dst)[128])
{
#pragma unroll
  for (int bt = 0; bt < 2; ++bt) {
    const unsigned short* p = base + (size_t)(bg0 + bt * 16 + lm) * rstride + koffA;
    s8v af[8];
    if (ATOM) {
      const unsigned long long* b64 = (const unsigned long long*)p;
#pragma unroll
      for (int s = 0; s < 8; ++s) {
        union { unsigned long long q[2]; s8v v; } u;
        u.q[0] = __hip_atomic_load(b64 + s * 8,     __ATOMIC_RELAXED, __HIP_MEMORY_SCOPE_AGENT);
        u.q[1] = __hip_atomic_load(b64 + s * 8 + 1, __ATOMIC_RELAXED, __HIP_MEMORY_SCOPE_AGENT);
        af[s] = u.v;
      }
    } else {
#pragma unroll
      for (int s = 0; s < 8; ++s) af[s] = *(const s8v*)(p + s * 32);
    }
    f4v acc[8];
#pragma unroll
    for (int ct = 0; ct < 8; ++ct) { f4v z = {0.f, 0.f, 0.f, 0.f}; acc[ct] = z; }
#pragma unroll
    for (int s = 0; s < 8; ++s)
#pragma unroll
      for (int ct = 0; ct < 8; ++ct)
        acc[ct] = __builtin_amdgcn_mfma_f32_16x16x32_bf16(af[s], breg[ct][s], acc[ct], 0, 0, 0);
#pragma unroll
    for (int ct = 0; ct < 8; ++ct)
#pragma unroll
      for (int r2 = 0; r2 < 4; ++r2)
        dst[bt * 16 + quad * 4 + r2][(ct * 16 + lm) ^ (quad << 4)] = acc[ct][r2];
  }
}

// All-4-layers pipelined persistent LSTM, 1 WG/CU, 128 gate-cols per WG.
//  256 WGs = 4L x 4 groups x 16 kaps. (lay,grp) = bid&15 -> a sync group's
//  16 WGs share bid mod 8 -> one XCD under round-robin (perf heuristic only).
//  Amplification of agent-scope h reads: 2048/128 = 16x (was 32x in R3) --
//  this kernel exists to halve coherence-point traffic per step.
//  waves 0-1 ("x waves"): x-partial for step t; layers >=1 read upstream ring
//    slot t&7 gated by upf >= t+2.
//  waves 2-3 ("h waves"): fused poll: lanes with (lane>>4)&1==0 check
//    ownf >= t+1; others check dnf >= t-6 (downstream finished step t-8 ->
//    its read of slot t&7 done before we overwrite).
//  Flag protocol (R2/R3-verified): syncB drains all h stores, tid0 stores
//    flag = t+2 agent-scope.
__global__ void __launch_bounds__(256, 1) lstm_all(
    const unsigned short* __restrict__ xin,   // (B,T,512) bf16, layer-0 input
    const unsigned short* __restrict__ wihb,  // (L,2048,512) bf16
    const unsigned short* __restrict__ whhb,  // (L,2048,512) bf16
    const float* __restrict__ bih,            // (L,2048)
    const float* __restrict__ bhh,            // (L,2048)
    const float* __restrict__ h0,             // (L,B,512) fp32
    const float* __restrict__ c0,             // (L,B,512) fp32
    unsigned short* __restrict__ ring,        // L * RING * B * 512 bf16
    unsigned int* __restrict__ bars,          // 16*16 epoch flags (zeroed)
    float* __restrict__ cout)                 // (L,B,512) fp32 final c
{
  const int tid  = threadIdx.x;
  const int wave = tid >> 6;
  const int lane = tid & 63;
  const int lm   = lane & 15;
  const int quad = lane >> 4;

  const int bid = blockIdx.x;
  const int lg  = bid & 15;       // (lay,grp) -> XCD under round-robin
  const int lay = lg >> 2;
  const int grp = lg & 3;
  const int kap = bid >> 4;       // hidden slice 0..15 (32 cols each)
  const int bg0 = grp * BB;

  __shared__ float xpart[2][BB][128];   // [x wave][batch][gate-col]
  __shared__ float hpart[2][BB][128];   // [h wave][batch][gate-col]

  const int isH = (wave >= 2);
  const unsigned short* wsel = (isH ? whhb : wihb) + (size_t)lay * G4 * HID;
  const int kbase = (wave & 1) * 256;

  // ---- weight fragments resident for all 1024 steps (256 VGPR/lane) ----
  // col-tile ct: gate = ct>>1, hidden half = ct&1 -> W row
  s8v breg[8][8];
#pragma unroll
  for (int ct = 0; ct < 8; ++ct) {
    const size_t grow = (size_t)((ct >> 1) * 512 + kap * 32 + (ct & 1) * 16 + lm);
#pragma unroll
    for (int s = 0; s < 8; ++s)
      breg[ct][s] = *(const s8v*)(wsel + grow * HID + kbase + s * 32 + quad * 8);
  }

  // ---- per-thread cell ownership: 4 cells (bi0 + 8j, kcol) ----
  const int kk   = tid & 31;      // 0..31 hidden col within slice
  const int bi0  = tid >> 5;      // 0..7
  const int kcol = kap * 32 + kk;

  float bias[4];
#pragma unroll
  for (int g = 0; g < 4; ++g)
    bias[g] = bih[lay * G4 + g * 512 + kcol] + bhh[lay * G4 + g * 512 + kcol];

  unsigned short* ringL = ring + (size_t)lay * RING * BATCH * HID;
  const unsigned short* ringUp = ring + (size_t)(lay - 1) * RING * BATCH * HID;

  // publish h0 = h(-1) into ring slot RING-1 through the coherence point
  float c[4];
#pragma unroll
  for (int j = 0; j < 4; ++j) {
    const int brow = bg0 + bi0 + j * 8;
    c[j] = c0[(size_t)lay * BATCH * HID + (size_t)brow * HID + kcol];
    unsigned short hb0 = f2bf(h0[(size_t)lay * BATCH * HID + (size_t)brow * HID + kcol]);
    unsigned hw0 = (unsigned)hb0 | (((unsigned)(unsigned short)__shfl_xor((int)hb0, 1, 64)) << 16);
    if ((tid & 1) == 0)
      __hip_atomic_store((unsigned*)(ringL + (size_t)(RING - 1) * BATCH * HID)
                             + (size_t)brow * (HID / 2) + (kcol >> 1),
                         hw0, __ATOMIC_RELAXED, __HIP_MEMORY_SCOPE_AGENT);
  }

  unsigned int* ownf = bars + lg * 16;
  unsigned int* upf  = ownf - NGRP * 16;   // deref'd only lay>0
  unsigned int* dnf  = (lay == LL - 1) ? ownf : ownf + NGRP * 16;

  const int koffA = kbase + quad * 8;

  __syncthreads();                   // drains h0 stores of every wave
  if (tid == 0)
    __hip_atomic_store(&ownf[kap], 1u, __ATOMIC_RELAXED, __HIP_MEMORY_SCOPE_AGENT);

  for (int t = 0; t < TSEQ; ++t) {
    if (!isH) {
      // ---- x waves: partial for step t (parallel with h waves) ----
      if (lay > 0) {
        pollv(upf, lane & 15, t + 2);   // upstream completed step t
        gemm32x128<true>(ringUp + (size_t)(t & (RING - 1)) * BATCH * HID,
                         (size_t)HID, bg0, lm, quad, koffA, breg, xpart[wave]);
      } else {
        gemm32x128<false>(xin + (size_t)t * HID, (size_t)TSEQ * HID,
                          bg0, lm, quad, koffA, breg, xpart[wave]);
      }
    } else {
      // ---- h waves: fused poll (own epoch + downstream back-pressure) ----
      const int dnside = (lane >> 4) & 1;
      pollv(dnside ? dnf : ownf, lane & 15, dnside ? (t - 6) : (t + 1));
      gemm32x128<true>(ringL + (size_t)((t - 1) & (RING - 1)) * BATCH * HID,
                       (size_t)HID, bg0, lm, quad, koffA, breg, hpart[wave - 2]);
    }

    __syncthreads();   // sync A: partials visible; all polls passed

    unsigned short hbv[4];
#pragma unroll
    for (int j = 0; j < 4; ++j) {
      const int bi = bi0 + j * 8;
      const int swz = ((bi >> 2) & 3) << 4;
      float gs[4];
#pragma unroll
      for (int g = 0; g < 4; ++g) {
        const int col = (g * 32 + kk) ^ swz;
        gs[g] = bias[g]
              + xpart[0][bi][col] + xpart[1][bi][col]
              + hpart[0][bi][col] + hpart[1][bi][col];
      }
      float ig = fsig(gs[0]);
      float fg = fsig(gs[1]);
      float gg = ftanh(gs[2]);
      float og = fsig(gs[3]);
      c[j] = fg * c[j] + ig * gg;
      hbv[j] = f2bf(og * ftanh(c[j]));
    }

    // publish h(t) into ring slot t&7 (recurrent readers + downstream layer)
    unsigned short* hdst = ringL + (size_t)(t & (RING - 1)) * BATCH * HID;
#pragma unroll
    for (int j = 0; j < 4; ++j) {
      unsigned hw = (unsigned)hbv[j] | (((unsigned)(unsigned short)__shfl_xor((int)hbv[j], 1, 64)) << 16);
      if ((tid & 1) == 0)
        __hip_atomic_store((unsigned*)hdst + (size_t)(bg0 + bi0 + j * 8) * (HID / 2) + (kcol >> 1),
                           hw, __ATOMIC_RELAXED, __HIP_MEMORY_SCOPE_AGENT);
    }

    __syncthreads();   // sync B: every wave's h stores drained (vmcnt(0)+s_barrier)
    if (tid == 0)
      __hip_atomic_store(&ownf[kap], (unsigned)(t + 2), __ATOMIC_RELAXED,
                         __HIP_MEMORY_SCOPE_AGENT);
  }

#pragma unroll
  for (int j = 0; j < 4; ++j)
    cout[(size_t)lay * BATCH * HID + (size_t)(bg0 + bi0 + j * 8) * HID + kcol] = c[j];
}

// ---------------------------------------------------------------------------
// Fallback: the proven per-layer kernel (verbatim; passes at ~13.4 ms).
// Used only if the cooperative capacity check / launch denies the pipelined
// kernel (e.g. VGPR/LDS rejection).
// ---------------------------------------------------------------------------
__global__ void __launch_bounds__(256, 1) lstm_layer(
    const unsigned short* __restrict__ xin,
    unsigned short* __restrict__ seqout,
    const unsigned short* __restrict__ wih,
    const unsigned short* __restrict__ whh,
    const float* __restrict__ bih,
    const float* __restrict__ bhh,
    const float* __restrict__ h0,
    const float* __restrict__ c0,
    unsigned short* __restrict__ hbuf,
    unsigned int* __restrict__ bars,
    float* __restrict__ cout,
    int write_seq)
{
  const int tid  = threadIdx.x;
  const int wave = tid >> 6;
  const int lane = tid & 63;
  const int lm   = lane & 15;
  const int quad = lane >> 4;

  const int bid = blockIdx.x;
  const int grp = bid & 7;
  const int kap = bid >> 3;
  const int bg0 = grp * 16;

  __shared__ float xpart[2][2][16][68];
  __shared__ float hpart[2][16][68];

  const int isH = (wave >= 2);
  const unsigned short* wsel = isH ? whh : wih;
  const int kbase = (wave & 1) * 256;

  s8v breg[4][8];
#pragma unroll
  for (int g = 0; g < 4; ++g) {
    const size_t row = (size_t)(g * 512 + kap * 16 + lm);
#pragma unroll
    for (int s = 0; s < 8; ++s)
      breg[g][s] = *(const s8v*)(wsel + row * HID + kbase + s * 32 + quad * 8);
  }

  const int b_i  = tid >> 4;
  const int kk   = tid & 15;
  const int kcol = kap * 16 + kk;
  const int brow = bg0 + b_i;

  float bias[4];
#pragma unroll
  for (int g = 0; g < 4; ++g) bias[g] = bih[g * 512 + kcol] + bhh[g * 512 + kcol];

  float c = c0[(size_t)brow * HID + kcol];

  {
    unsigned short hb0 = f2bf(h0[(size_t)brow * HID + kcol]);
    unsigned hw0 = (unsigned)hb0 | (((unsigned)(unsigned short)__shfl_xor((int)hb0, 1, 64)) << 16);
    if ((tid & 1) == 0)
      __hip_atomic_store((unsigned*)hbuf + (size_t)brow * (HID / 2) + (kcol >> 1),
                         hw0, __ATOMIC_RELAXED, __HIP_MEMORY_SCOPE_AGENT);
  }

  unsigned int* flags = bars + grp * 32;

  const int arow = bg0 + lm;
  const size_t xrowbase = (size_t)arow * TSEQ * HID;
  const int koffA = kbase + quad * 8;

  if (!isH) {
    const unsigned short* xb = xin + xrowbase + koffA;
    s8v af[8];
#pragma unroll
    for (int s = 0; s < 8; ++s) af[s] = *(const s8v*)(xb + s * 32);
    f4v acc[4];
#pragma unroll
    for (int g = 0; g < 4; ++g) { f4v z = {0.f, 0.f, 0.f, 0.f}; acc[g] = z; }
#pragma unroll
    for (int s = 0; s < 8; ++s)
#pragma unroll
      for (int g = 0; g < 4; ++g)
        acc[g] = __builtin_amdgcn_mfma_f32_16x16x32_bf16(af[s], breg[g][s], acc[g], 0, 0, 0);
#pragma unroll
    for (int g = 0; g < 4; ++g)
#pragma unroll
      for (int r = 0; r < 4; ++r)
        xpart[0][wave][quad * 4 + r][g * 16 + lm] = acc[g][r];
  }

  __syncthreads();
  if (tid == 0)
    __hip_atomic_store(&flags[kap], 1u, __ATOMIC_RELAXED, __HIP_MEMORY_SCOPE_AGENT);

  for (int t = 0; t < TSEQ; ++t) {
    if (!isH) {
      if (t + 1 < TSEQ) {
        const unsigned short* xb = xin + xrowbase + (size_t)(t + 1) * HID + koffA;
        s8v af[8];
#pragma unroll
        for (int s = 0; s < 8; ++s) af[s] = *(const s8v*)(xb + s * 32);
        f4v acc[4];
#pragma unroll
        for (int g = 0; g < 4; ++g) { f4v z = {0.f, 0.f, 0.f, 0.f}; acc[g] = z; }
#pragma unroll
        for (int s = 0; s < 8; ++s)
#pragma unroll
          for (int g = 0; g < 4; ++g)
            acc[g] = __builtin_amdgcn_mfma_f32_16x16x32_bf16(af[s], breg[g][s], acc[g], 0, 0, 0);
#pragma unroll
        for (int g = 0; g < 4; ++g)
#pragma unroll
          for (int r = 0; r < 4; ++r)
            xpart[(t + 1) & 1][wave][quad * 4 + r][g * 16 + lm] = acc[g][r];
      }
    } else {
      const unsigned tgt = (unsigned)(t + 1);
      for (int guard = 0; guard < (1 << 15); ++guard) {
        unsigned f = __hip_atomic_load(&flags[lane & 31], __ATOMIC_RELAXED,
                                       __HIP_MEMORY_SCOPE_AGENT);
        if (__all((int)(f >= tgt))) break;
      }
      asm volatile("" ::: "memory");
      const unsigned short* hprev = hbuf + (size_t)(t & 1) * BATCH * HID;
      const unsigned long long* hb64 =
          (const unsigned long long*)(hprev + (size_t)arow * HID + koffA);
      union { unsigned long long q[16]; s8v v[8]; } ua;
#pragma unroll
      for (int s = 0; s < 8; ++s) {
        ua.q[2 * s]     = __hip_atomic_load(hb64 + s * 8,     __ATOMIC_RELAXED, __HIP_MEMORY_SCOPE_AGENT);
        ua.q[2 * s + 1] = __hip_atomic_load(hb64 + s * 8 + 1, __ATOMIC_RELAXED, __HIP_MEMORY_SCOPE_AGENT);
      }
      f4v acc[4];
#pragma unroll
      for (int g = 0; g < 4; ++g) { f4v z = {0.f, 0.f, 0.f, 0.f}; acc[g] = z; }
#pragma unroll
      for (int s = 0; s < 8; ++s)
#pragma unroll
        for (int g = 0; g < 4; ++g)
          acc[g] = __builtin_amdgcn_mfma_f32_16x16x32_bf16(ua.v[s], breg[g][s], acc[g], 0, 0, 0);
#pragma unroll
      for (int g = 0; g < 4; ++g)
#pragma unroll
        for (int r = 0; r < 4; ++r)
          hpart[wave - 2][quad * 4 + r][g * 16 + lm] = acc[g][r];
    }

    __syncthreads();

    float gs[4];
#pragma unroll
    for (int g = 0; g < 4; ++g)
      gs[g] = bias[g]
            + xpart[t & 1][0][b_i][g * 16 + kk] + xpart[t & 1][1][b_i][g * 16 + kk]
            + hpart[0][b_i][g * 16 + kk]        + hpart[1][b_i][g * 16 + kk];

    float ig = fsig(gs[0]);
    float fg = fsig(gs[1]);
    float gg = ftanh(gs[2]);
    float og = fsig(gs[3]);
    c = fg * c + ig * gg;
    float h = og * ftanh(c);
    unsigned short hb = f2bf(h);

    unsigned hw = (unsigned)hb | (((unsigned)(unsigned short)__shfl_xor((int)hb, 1, 64)) << 16);
    unsigned short* hnext = hbuf + (size_t)((t & 1) ^ 1) * BATCH * HID;
    if ((tid & 1) == 0) {
      __hip_atomic_store((unsigned*)hnext + (size_t)brow * (HID / 2) + (kcol >> 1),
                         hw, __ATOMIC_RELAXED, __HIP_MEMORY_SCOPE_AGENT);
      if (write_seq)
        ((unsigned*)seqout)[((size_t)brow * TSEQ + t) * (HID / 2) + (kcol >> 1)] = hw;
    }

    __syncthreads();
    if (tid == 0)
      __hip_atomic_store(&flags[kap], (unsigned)(t + 2), __ATOMIC_RELAXED,
                         __HIP_MEMORY_SCOPE_AGENT);
  }

  cout[(size_t)brow * HID + kcol] = c;
}

extern "C" void kernel_launch(void* const* d_in, const int* in_sizes, int n_in,
                              void* d_out, int out_size, void* d_ws, size_t ws_size,
                              hipStream_t stream)
{
  (void)in_sizes; (void)n_in; (void)out_size;
  const float* x   = (const float*)d_in[0];
  const float* h0  = (const float*)d_in[1];
  const float* c0  = (const float*)d_in[2];
  const float* wih = (const float*)d_in[3];
  const float* whh = (const float*)d_in[4];
  const float* bih = (const float*)d_in[5];
  const float* bhh = (const float*)d_in[6];
  float* out = (float*)d_out;

  const size_t seq_elems  = (size_t)BATCH * TSEQ * HID;          // 67,108,864
  const size_t w_elems    = (size_t)LL * G4 * HID;               // 4,194,304

  // R4 layout + shared flag region; coop ring overlays seqB (unused by coop).
  unsigned short* seqA  = (unsigned short*)d_ws;
  unsigned short* seqB  = seqA + seq_elems;
  unsigned short* wihb  = seqB + seq_elems;
  unsigned short* whhb  = wihb + w_elems;
  unsigned short* hbuf  = whhb + w_elems;                        // fallback only
  unsigned int*   bars  = (unsigned int*)(hbuf + 2 * (size_t)BATCH * HID);
  unsigned short* ringb = seqB;                                  // coop only

  size_t need = (2 * seq_elems + 2 * w_elems + 2 * (size_t)BATCH * HID) * 2
              + (size_t)256 * 4;
  if (ws_size < need) return;  // fail visibly rather than corrupt memory

  cvt_f32_bf16<<<4096, 256, 0, stream>>>(x,   seqA, (int)(seq_elems / 4));
  cvt_f32_bf16<<<2048, 256, 0, stream>>>(wih, wihb, (int)(w_elems / 4));
  cvt_f32_bf16<<<2048, 256, 0, stream>>>(whh, whhb, (int)(w_elems / 4));

  // ---- capacity check for the 256-WG cooperative pipeline (cached) ----
  static int coop_capacity = -1;
  if (coop_capacity < 0) {
    int nb = 0, ncu = 0, dev = 0;
    hipGetDevice(&dev);
    hipOccupancyMaxActiveBlocksPerMultiprocessor(&nb, (const void*)lstm_all, 256, 0);
    hipDeviceGetAttribute(&ncu, hipDeviceAttributeMultiprocessorCount, dev);
    coop_capacity = nb * ncu;
  }

  bool done = false;
  if (coop_capacity >= LL * NGRP * KAP16) {
    hipMemsetAsync(bars, 0, 16 * 16 * sizeof(unsigned), stream);
    const unsigned short* xp   = seqA;
    const unsigned short* wihp = wihb;
    const unsigned short* whhp = whhb;
    const float* bihp = bih;
    const float* bhhp = bhh;
    const float* h0p  = h0;
    const float* c0p  = c0;
    unsigned short* ringp = ringb;
    unsigned int*   barsp = bars;
    float* coutp = out;
    void* args[] = { &xp, &wihp, &whhp, &bihp, &bhhp, &h0p, &c0p,
                     &ringp, &barsp, &coutp };
    done = hipLaunchCooperativeKernel(lstm_all, dim3(LL * NGRP * KAP16), dim3(256),
                                      args, 0, stream) == hipSuccess;
  }

  if (!done) {
    // ---- proven per-layer path ----
    for (int l = 0; l < LL; ++l) {
      hipMemsetAsync(bars, 0, 8 * 32 * sizeof(unsigned), stream);
      const unsigned short* in_p  = (l & 1) ? seqB : seqA;
      unsigned short*       out_p = (l & 1) ? seqA : seqB;
      const unsigned short* wih_p = wihb + (size_t)l * G4 * HID;
      const unsigned short* whh_p = whhb + (size_t)l * G4 * HID;
      const float* bih_p = bih + l * G4;
      const float* bhh_p = bhh + l * G4;
      const float* h0_p  = h0 + (size_t)l * BATCH * HID;
      const float* c0_p  = c0 + (size_t)l * BATCH * HID;
      float* cout_p = out + (size_t)l * BATCH * HID;
      int wsflag = (l < LL - 1) ? 1 : 0;
      unsigned short* hbuf_p = hbuf;
      unsigned int* bars_p = bars;
      void* args[] = { &in_p, &out_p, &wih_p, &whh_p, &bih_p, &bhh_p,
                       &h0_p, &c0_p, &hbuf_p, &bars_p, &cout_p, &wsflag };
      hipLaunchCooperativeKernel(lstm_layer, dim3(256), dim3(256), args, 0, stream);
    }
  }
}

// Round 6
// 6668.327 us; speedup vs baseline: 2.0142x; 2.0142x over previous
//
#include <hip/hip_runtime.h>
#include <stdint.h>

#define LL 4
#define BATCH 128
#define TSEQ 1024
#define HID 512
#define G4 2048
#define NG 2      // pipelined kernel: batch groups per layer (64 batches each)
#define BB 64     // batches per group (4 MFMA row-tiles)
#define KAPS 32   // hidden-slice WGs per group (16 cols each)
#define TD 256    // trace depth (slots) == steps per dispatch
#define NDISP 4   // dispatches (TD*NDISP == TSEQ)

typedef __attribute__((ext_vector_type(8))) short s8v;   // 8 x bf16 fragment
typedef __attribute__((ext_vector_type(4))) float f4v;   // MFMA accumulator

__device__ __forceinline__ unsigned short f2bf(float f) {
  union { float f; unsigned u; } v; v.f = f;
  return (unsigned short)((v.u + 0x7fffu + ((v.u >> 16) & 1u)) >> 16);  // RNE
}

__device__ __forceinline__ float fsig(float x) { return 1.f / (1.f + __expf(-x)); }

__device__ __forceinline__ float ftanh(float x) {
  float a = __builtin_fabsf(x);
  float e = __expf(-2.f * a);
  float t = (1.f - e) / (1.f + e);
  return x < 0.f ? -t : t;
}

__global__ void cvt_f32_bf16(const float* __restrict__ in, unsigned short* __restrict__ out, int n4) {
  int stride = gridDim.x * blockDim.x;
  for (int i = blockIdx.x * blockDim.x + threadIdx.x; i < n4; i += stride) {
    f4v v = ((const f4v*)in)[i];
    union { unsigned short u[4]; unsigned long long d; } o;
    o.u[0] = f2bf(v.x); o.u[1] = f2bf(v.y); o.u[2] = f2bf(v.z); o.u[3] = f2bf(v.w);
    ((unsigned long long*)out)[i] = o.d;
  }
}

// Bounded flag spin with s_sleep backoff. Guard expiry -> wrong answer, never a hang.
__device__ __forceinline__ void pollv(const unsigned int* p, int idx, int tgt) {
  unsigned f = __hip_atomic_load(&p[idx], __ATOMIC_RELAXED, __HIP_MEMORY_SCOPE_AGENT);
  if (!__all((int)f >= tgt)) {
    for (int guard = 0; guard < (1 << 17); ++guard) {
      __builtin_amdgcn_s_sleep(1);
      f = __hip_atomic_load(&p[idx], __ATOMIC_RELAXED, __HIP_MEMORY_SCOPE_AGENT);
      if (__all((int)f >= tgt)) break;
    }
  }
  asm volatile("" ::: "memory");  // no compiler motion of data loads above the poll
}

// Four 16-batch row tiles -> partial[64][64]; PLAIN vector loads (16B).
// Freshness argument (why plain is safe here): every source address is either
//  (a) pre-dispatch data (xin), or (b) a trace slot written exactly once per
//  dispatch, read only after the producer's agent-store + flag round trip put
//  it in the LLC, and never re-read after its single rewrite within a
//  dispatch window. Dispatch-boundary cache invalidation covers slot reuse
//  across dispatches. So no L1/L2 line can serve stale data.
// D layout (m89): col = lane&15, row = quad*4 + reg.
// Bank swizzle (R3-verified, 0 conflicts): phys col = col ^ ((((row>>2)^row)&1)<<4).
__device__ __forceinline__ void gemm64(
    const unsigned short* __restrict__ base, size_t rstride,
    int bg0, int lm, int quad, int koffA,
    const s8v (&breg)[4][8], float (*dst)[64])
{
#pragma unroll
  for (int bt = 0; bt < 4; ++bt) {
    const unsigned short* p = base + (size_t)(bg0 + bt * 16 + lm) * rstride + koffA;
    s8v af[8];
#pragma unroll
    for (int s = 0; s < 8; ++s) af[s] = *(const s8v*)(p + s * 32);
    f4v acc[4];
#pragma unroll
    for (int g = 0; g < 4; ++g) { f4v z = {0.f, 0.f, 0.f, 0.f}; acc[g] = z; }
#pragma unroll
    for (int s = 0; s < 8; ++s)
#pragma unroll
      for (int g = 0; g < 4; ++g)
        acc[g] = __builtin_amdgcn_mfma_f32_16x16x32_bf16(af[s], breg[g][s], acc[g], 0, 0, 0);
#pragma unroll
    for (int g = 0; g < 4; ++g)
#pragma unroll
      for (int r2 = 0; r2 < 4; ++r2) {
        const int row = bt * 16 + quad * 4 + r2;
        const int swz = (((row >> 2) ^ row) & 1) << 4;
        dst[row][(g * 16 + lm) ^ swz] = acc[g][r2];
      }
  }
}

// All-4-layers pipelined persistent LSTM; 4 sequential cooperative dispatches
// of TD=256 steps each over a 256-slot h trace (slot = t & 255).
//  256 WGs = 4 layers x 2 groups x 32 hidden slices, 1 WG/CU (R3 resources).
//  Producers publish h(t) with agent-scope stores + flag t+2 after syncB
//  (R0/R3-verified protocol) -> data at LLC before any reader's poll passes.
//  Consumers use PLAIN 16B loads: first touch per XCD misses to LLC, the
//  other WGs of the group are served by their XCD L2 -> agent-path traffic
//  drops ~20x vs R3/R4. No back-pressure poll needed (slack 256 = window).
//  c-state is carried across dispatches in cstate (== the output buffer, so
//  the final dispatch leaves exactly the expected (L,B,H) final-c tensor).
__global__ void __launch_bounds__(256, 1) lstm_all(
    const unsigned short* __restrict__ xin,   // (B,T,512) bf16, layer-0 input
    const unsigned short* __restrict__ wihb,  // (L,2048,512) bf16
    const unsigned short* __restrict__ whhb,  // (L,2048,512) bf16
    const float* __restrict__ bih,            // (L,2048)
    const float* __restrict__ bhh,            // (L,2048)
    const float* __restrict__ h0,             // (L,B,512) fp32
    const float* __restrict__ c0,             // (L,B,512) fp32
    unsigned short* __restrict__ trace,       // L * TD * B * 512 bf16
    unsigned int* __restrict__ bars,          // 8*32 epoch flags (zeroed at t0=0)
    float* __restrict__ cstate,               // (L,B,512) fp32 carried c (== out)
    int t0)                                   // first global step of this dispatch
{
  const int tid  = threadIdx.x;
  const int wave = tid >> 6;
  const int lane = tid & 63;
  const int lm   = lane & 15;
  const int quad = lane >> 4;

  const int bid = blockIdx.x;
  const int xg  = bid & 7;        // (lay,grp): a sync group's 32 WGs share bid%8
  const int lay = xg >> 1;
  const int grp = xg & 1;
  const int kap = bid >> 3;       // hidden slice 0..31
  const int bg0 = grp * BB;

  __shared__ float xpart[2][BB][64];   // [x wave][batch][gate] (current step)
  __shared__ float hpart[2][BB][64];   // [h wave][batch][gate]

  const int isH = (wave >= 2);
  const unsigned short* wsel = (isH ? whhb : wihb) + (size_t)lay * G4 * HID;
  const int kbase = (wave & 1) * 256;

  // ---- weight fragments resident for the dispatch ----
  s8v breg[4][8];
#pragma unroll
  for (int g = 0; g < 4; ++g) {
    const size_t row = (size_t)(g * 512 + kap * 16 + lm);
#pragma unroll
    for (int s = 0; s < 8; ++s)
      breg[g][s] = *(const s8v*)(wsel + row * HID + kbase + s * 32 + quad * 8);
  }

  // ---- per-thread cell ownership: 4 cells (bi0 + 16j) x col kcol ----
  const int bi0  = tid >> 4;      // 0..15
  const int kk   = tid & 15;
  const int kcol = kap * 16 + kk;

  float bias[4];
#pragma unroll
  for (int g = 0; g < 4; ++g)
    bias[g] = bih[lay * G4 + g * 512 + kcol] + bhh[lay * G4 + g * 512 + kcol];

  unsigned short* trL = trace + (size_t)lay * TD * BATCH * HID;
  const unsigned short* trUp = trace + (size_t)(lay - 1) * TD * BATCH * HID;

  float c[4];
  if (t0 == 0) {
    // dispatch 0: c from c0; publish h0 = h(-1) into trace slot TD-1 (agent)
#pragma unroll
    for (int j = 0; j < 4; ++j) {
      const int brow = bg0 + bi0 + j * 16;
      c[j] = c0[(size_t)lay * BATCH * HID + (size_t)brow * HID + kcol];
      unsigned short hb0 = f2bf(h0[(size_t)lay * BATCH * HID + (size_t)brow * HID + kcol]);
      unsigned hw0 = (unsigned)hb0 | (((unsigned)(unsigned short)__shfl_xor((int)hb0, 1, 64)) << 16);
      if ((tid & 1) == 0)
        __hip_atomic_store((unsigned*)(trL + (size_t)(TD - 1) * BATCH * HID)
                               + (size_t)brow * (HID / 2) + (kcol >> 1),
                           hw0, __ATOMIC_RELAXED, __HIP_MEMORY_SCOPE_AGENT);
    }
  } else {
    // later dispatches: c carried in cstate (plain load; cross-dispatch
    // visibility guaranteed by dispatch-boundary release/acquire)
#pragma unroll
    for (int j = 0; j < 4; ++j)
      c[j] = cstate[(size_t)lay * BATCH * HID + (size_t)(bg0 + bi0 + j * 16) * HID + kcol];
  }

  unsigned int* ownf = bars + (xg << 5);
  unsigned int* upf  = ownf - (NG << 5);   // deref'd only lay>0

  const int koffA = kbase + quad * 8;

  __syncthreads();                   // drains h0 stores of every wave
  if (tid == 0 && t0 == 0)
    __hip_atomic_store(&ownf[kap], 1u, __ATOMIC_RELAXED, __HIP_MEMORY_SCOPE_AGENT);
  // t0>0: flags persist from the previous dispatch (hold t0+1 already)

  for (int t = t0; t < t0 + TD; ++t) {
    if (!isH) {
      // ---- x waves: partial for step t (parallel with h waves) ----
      if (lay > 0) {
        pollv(upf, lane & 31, t + 2);   // upstream completed step t -> slot t&255 at LLC
        gemm64(trUp + (size_t)(t & (TD - 1)) * BATCH * HID,
               (size_t)HID, bg0, lm, quad, koffA, breg, xpart[wave]);
      } else {
        gemm64(xin + (size_t)t * HID, (size_t)TSEQ * HID,
               bg0, lm, quad, koffA, breg, xpart[wave]);
      }
    } else {
      // ---- h waves: own epoch poll (no back-pressure needed: slack = TD) ----
      pollv(ownf, lane & 31, t + 1);
      gemm64(trL + (size_t)((t - 1) & (TD - 1)) * BATCH * HID,
             (size_t)HID, bg0, lm, quad, koffA, breg, hpart[wave - 2]);
    }

    __syncthreads();   // sync A: partials visible; all polls passed

    unsigned short hbv[4];
#pragma unroll
    for (int j = 0; j < 4; ++j) {
      const int bi = bi0 + j * 16;
      const int swz = ((((bi >> 2) ^ bi) & 1) << 4);
      float gs[4];
#pragma unroll
      for (int g = 0; g < 4; ++g) {
        const int col = (g * 16 + kk) ^ swz;
        gs[g] = bias[g]
              + xpart[0][bi][col] + xpart[1][bi][col]
              + hpart[0][bi][col] + hpart[1][bi][col];
      }
      float ig = fsig(gs[0]);
      float fg = fsig(gs[1]);
      float gg = ftanh(gs[2]);
      float og = fsig(gs[3]);
      c[j] = fg * c[j] + ig * gg;
      hbv[j] = f2bf(og * ftanh(c[j]));
    }

    // publish h(t) into trace slot t&255 (agent stores: data -> LLC)
    unsigned short* hdst = trL + (size_t)(t & (TD - 1)) * BATCH * HID;
#pragma unroll
    for (int j = 0; j < 4; ++j) {
      unsigned hw = (unsigned)hbv[j] | (((unsigned)(unsigned short)__shfl_xor((int)hbv[j], 1, 64)) << 16);
      if ((tid & 1) == 0)
        __hip_atomic_store((unsigned*)hdst + (size_t)(bg0 + bi0 + j * 16) * (HID / 2) + (kcol >> 1),
                           hw, __ATOMIC_RELAXED, __HIP_MEMORY_SCOPE_AGENT);
    }

    __syncthreads();   // sync B: every wave's h stores drained (vmcnt(0)+s_barrier)
    if (tid == 0)
      __hip_atomic_store(&ownf[kap], (unsigned)(t + 2), __ATOMIC_RELAXED,
                         __HIP_MEMORY_SCOPE_AGENT);
  }

  // carry c to the next dispatch (final dispatch: this IS the output)
#pragma unroll
  for (int j = 0; j < 4; ++j)
    cstate[(size_t)lay * BATCH * HID + (size_t)(bg0 + bi0 + j * 16) * HID + kcol] = c[j];
}

// ---------------------------------------------------------------------------
// Fallback: the proven per-layer kernel (verbatim; passes at ~13.4 ms).
// Used only if the cooperative capacity check / launch denies the pipeline.
// ---------------------------------------------------------------------------
__global__ void __launch_bounds__(256, 1) lstm_layer(
    const unsigned short* __restrict__ xin,
    unsigned short* __restrict__ seqout,
    const unsigned short* __restrict__ wih,
    const unsigned short* __restrict__ whh,
    const float* __restrict__ bih,
    const float* __restrict__ bhh,
    const float* __restrict__ h0,
    const float* __restrict__ c0,
    unsigned short* __restrict__ hbuf,
    unsigned int* __restrict__ bars,
    float* __restrict__ cout,
    int write_seq)
{
  const int tid  = threadIdx.x;
  const int wave = tid >> 6;
  const int lane = tid & 63;
  const int lm   = lane & 15;
  const int quad = lane >> 4;

  const int bid = blockIdx.x;
  const int grp = bid & 7;
  const int kap = bid >> 3;
  const int bg0 = grp * 16;

  __shared__ float xpart[2][2][16][68];
  __shared__ float hpart[2][16][68];

  const int isH = (wave >= 2);
  const unsigned short* wsel = isH ? whh : wih;
  const int kbase = (wave & 1) * 256;

  s8v breg[4][8];
#pragma unroll
  for (int g = 0; g < 4; ++g) {
    const size_t row = (size_t)(g * 512 + kap * 16 + lm);
#pragma unroll
    for (int s = 0; s < 8; ++s)
      breg[g][s] = *(const s8v*)(wsel + row * HID + kbase + s * 32 + quad * 8);
  }

  const int b_i  = tid >> 4;
  const int kk   = tid & 15;
  const int kcol = kap * 16 + kk;
  const int brow = bg0 + b_i;

  float bias[4];
#pragma unroll
  for (int g = 0; g < 4; ++g) bias[g] = bih[g * 512 + kcol] + bhh[g * 512 + kcol];

  float c = c0[(size_t)brow * HID + kcol];

  {
    unsigned short hb0 = f2bf(h0[(size_t)brow * HID + kcol]);
    unsigned hw0 = (unsigned)hb0 | (((unsigned)(unsigned short)__shfl_xor((int)hb0, 1, 64)) << 16);
    if ((tid & 1) == 0)
      __hip_atomic_store((unsigned*)hbuf + (size_t)brow * (HID / 2) + (kcol >> 1),
                         hw0, __ATOMIC_RELAXED, __HIP_MEMORY_SCOPE_AGENT);
  }

  unsigned int* flags = bars + grp * 32;

  const int arow = bg0 + lm;
  const size_t xrowbase = (size_t)arow * TSEQ * HID;
  const int koffA = kbase + quad * 8;

  if (!isH) {
    const unsigned short* xb = xin + xrowbase + koffA;
    s8v af[8];
#pragma unroll
    for (int s = 0; s < 8; ++s) af[s] = *(const s8v*)(xb + s * 32);
    f4v acc[4];
#pragma unroll
    for (int g = 0; g < 4; ++g) { f4v z = {0.f, 0.f, 0.f, 0.f}; acc[g] = z; }
#pragma unroll
    for (int s = 0; s < 8; ++s)
#pragma unroll
      for (int g = 0; g < 4; ++g)
        acc[g] = __builtin_amdgcn_mfma_f32_16x16x32_bf16(af[s], breg[g][s], acc[g], 0, 0, 0);
#pragma unroll
    for (int g = 0; g < 4; ++g)
#pragma unroll
      for (int r = 0; r < 4; ++r)
        xpart[0][wave][quad * 4 + r][g * 16 + lm] = acc[g][r];
  }

  __syncthreads();
  if (tid == 0)
    __hip_atomic_store(&flags[kap], 1u, __ATOMIC_RELAXED, __HIP_MEMORY_SCOPE_AGENT);

  for (int t = 0; t < TSEQ; ++t) {
    if (!isH) {
      if (t + 1 < TSEQ) {
        const unsigned short* xb = xin + xrowbase + (size_t)(t + 1) * HID + koffA;
        s8v af[8];
#pragma unroll
        for (int s = 0; s < 8; ++s) af[s] = *(const s8v*)(xb + s * 32);
        f4v acc[4];
#pragma unroll
        for (int g = 0; g < 4; ++g) { f4v z = {0.f, 0.f, 0.f, 0.f}; acc[g] = z; }
#pragma unroll
        for (int s = 0; s < 8; ++s)
#pragma unroll
          for (int g = 0; g < 4; ++g)
            acc[g] = __builtin_amdgcn_mfma_f32_16x16x32_bf16(af[s], breg[g][s], acc[g], 0, 0, 0);
#pragma unroll
        for (int g = 0; g < 4; ++g)
#pragma unroll
          for (int r = 0; r < 4; ++r)
            xpart[(t + 1) & 1][wave][quad * 4 + r][g * 16 + lm] = acc[g][r];
      }
    } else {
      const unsigned tgt = (unsigned)(t + 1);
      for (int guard = 0; guard < (1 << 15); ++guard) {
        unsigned f = __hip_atomic_load(&flags[lane & 31], __ATOMIC_RELAXED,
                                       __HIP_MEMORY_SCOPE_AGENT);
        if (__all((int)(f >= tgt))) break;
      }
      asm volatile("" ::: "memory");
      const unsigned short* hprev = hbuf + (size_t)(t & 1) * BATCH * HID;
      const unsigned long long* hb64 =
          (const unsigned long long*)(hprev + (size_t)arow * HID + koffA);
      union { unsigned long long q[16]; s8v v[8]; } ua;
#pragma unroll
      for (int s = 0; s < 8; ++s) {
        ua.q[2 * s]     = __hip_atomic_load(hb64 + s * 8,     __ATOMIC_RELAXED, __HIP_MEMORY_SCOPE_AGENT);
        ua.q[2 * s + 1] = __hip_atomic_load(hb64 + s * 8 + 1, __ATOMIC_RELAXED, __HIP_MEMORY_SCOPE_AGENT);
      }
      f4v acc[4];
#pragma unroll
      for (int g = 0; g < 4; ++g) { f4v z = {0.f, 0.f, 0.f, 0.f}; acc[g] = z; }
#pragma unroll
      for (int s = 0; s < 8; ++s)
#pragma unroll
        for (int g = 0; g < 4; ++g)
          acc[g] = __builtin_amdgcn_mfma_f32_16x16x32_bf16(ua.v[s], breg[g][s], acc[g], 0, 0, 0);
#pragma unroll
      for (int g = 0; g < 4; ++g)
#pragma unroll
        for (int r = 0; r < 4; ++r)
          hpart[wave - 2][quad * 4 + r][g * 16 + lm] = acc[g][r];
    }

    __syncthreads();

    float gs[4];
#pragma unroll
    for (int g = 0; g < 4; ++g)
      gs[g] = bias[g]
            + xpart[t & 1][0][b_i][g * 16 + kk] + xpart[t & 1][1][b_i][g * 16 + kk]
            + hpart[0][b_i][g * 16 + kk]        + hpart[1][b_i][g * 16 + kk];

    float ig = fsig(gs[0]);
    float fg = fsig(gs[1]);
    float gg = ftanh(gs[2]);
    float og = fsig(gs[3]);
    c = fg * c + ig * gg;
    float h = og * ftanh(c);
    unsigned short hb = f2bf(h);

    unsigned hw = (unsigned)hb | (((unsigned)(unsigned short)__shfl_xor((int)hb, 1, 64)) << 16);
    unsigned short* hnext = hbuf + (size_t)((t & 1) ^ 1) * BATCH * HID;
    if ((tid & 1) == 0) {
      __hip_atomic_store((unsigned*)hnext + (size_t)brow * (HID / 2) + (kcol >> 1),
                         hw, __ATOMIC_RELAXED, __HIP_MEMORY_SCOPE_AGENT);
      if (write_seq)
        ((unsigned*)seqout)[((size_t)brow * TSEQ + t) * (HID / 2) + (kcol >> 1)] = hw;
    }

    __syncthreads();
    if (tid == 0)
      __hip_atomic_store(&flags[kap], (unsigned)(t + 2), __ATOMIC_RELAXED,
                         __HIP_MEMORY_SCOPE_AGENT);
  }

  cout[(size_t)brow * HID + kcol] = c;
}

extern "C" void kernel_launch(void* const* d_in, const int* in_sizes, int n_in,
                              void* d_out, int out_size, void* d_ws, size_t ws_size,
                              hipStream_t stream)
{
  (void)in_sizes; (void)n_in; (void)out_size;
  const float* x   = (const float*)d_in[0];
  const float* h0  = (const float*)d_in[1];
  const float* c0  = (const float*)d_in[2];
  const float* wih = (const float*)d_in[3];
  const float* whh = (const float*)d_in[4];
  const float* bih = (const float*)d_in[5];
  const float* bhh = (const float*)d_in[6];
  float* out = (float*)d_out;

  const size_t seq_elems = (size_t)BATCH * TSEQ * HID;           // 67,108,864
  const size_t w_elems   = (size_t)LL * G4 * HID;                // 4,194,304
  // trace = LL*TD*BATCH*HID = 4*256*128*512 = 67,108,864 == seq_elems (exact
  // overlay of the seqB region -> workspace need unchanged from proven runs)

  unsigned short* seqA  = (unsigned short*)d_ws;
  unsigned short* seqB  = seqA + seq_elems;
  unsigned short* wihb  = seqB + seq_elems;
  unsigned short* whhb  = wihb + w_elems;
  unsigned short* hbuf  = whhb + w_elems;                        // fallback only
  unsigned int*   bars  = (unsigned int*)(hbuf + 2 * (size_t)BATCH * HID);
  unsigned short* traceb = seqB;                                 // coop only

  size_t need = (2 * seq_elems + 2 * w_elems + 2 * (size_t)BATCH * HID) * 2
              + (size_t)256 * 4;
  if (ws_size < need) return;  // fail visibly rather than corrupt memory

  cvt_f32_bf16<<<4096, 256, 0, stream>>>(x,   seqA, (int)(seq_elems / 4));
  cvt_f32_bf16<<<2048, 256, 0, stream>>>(wih, wihb, (int)(w_elems / 4));
  cvt_f32_bf16<<<2048, 256, 0, stream>>>(whh, whhb, (int)(w_elems / 4));

  // ---- capacity check for the 256-WG cooperative pipeline (cached) ----
  static int coop_capacity = -1;
  if (coop_capacity < 0) {
    int nb = 0, ncu = 0, dev = 0;
    hipGetDevice(&dev);
    hipOccupancyMaxActiveBlocksPerMultiprocessor(&nb, (const void*)lstm_all, 256, 0);
    hipDeviceGetAttribute(&ncu, hipDeviceAttributeMultiprocessorCount, dev);
    coop_capacity = nb * ncu;
  }

  bool done = false;
  if (coop_capacity >= LL * NG * KAPS) {
    hipMemsetAsync(bars, 0, 8 * 32 * sizeof(unsigned), stream);
    const unsigned short* xp   = seqA;
    const unsigned short* wihp = wihb;
    const unsigned short* whhp = whhb;
    const float* bihp = bih;
    const float* bhhp = bhh;
    const float* h0p  = h0;
    const float* c0p  = c0;
    unsigned short* trp  = traceb;
    unsigned int*   barsp = bars;
    float* cstp = out;               // c-state carrier == final output buffer
    int t0s[NDISP];
    bool ok = true;
    for (int kd = 0; kd < NDISP && ok; ++kd) {
      t0s[kd] = kd * TD;
      void* args[] = { &xp, &wihp, &whhp, &bihp, &bhhp, &h0p, &c0p,
                       &trp, &barsp, &cstp, &t0s[kd] };
      ok = hipLaunchCooperativeKernel(lstm_all, dim3(LL * NG * KAPS), dim3(256),
                                      args, 0, stream) == hipSuccess;
    }
    done = ok;
  }

  if (!done) {
    // ---- proven per-layer path (recomputes everything; trace scribbles are
    // harmless since it uses hbuf, and it fully rewrites out) ----
    for (int l = 0; l < LL; ++l) {
      hipMemsetAsync(bars, 0, 8 * 32 * sizeof(unsigned), stream);
      const unsigned short* in_p  = (l & 1) ? seqB : seqA;
      unsigned short*       out_p = (l & 1) ? seqA : seqB;
      const unsigned short* wih_p = wihb + (size_t)l * G4 * HID;
      const unsigned short* whh_p = whhb + (size_t)l * G4 * HID;
      const float* bih_p = bih + l * G4;
      const float* bhh_p = bhh + l * G4;
      const float* h0_p  = h0 + (size_t)l * BATCH * HID;
      const float* c0_p  = c0 + (size_t)l * BATCH * HID;
      float* cout_p = out + (size_t)l * BATCH * HID;
      int wsflag = (l < LL - 1) ? 1 : 0;
      unsigned short* hbuf_p = hbuf;
      unsigned int* bars_p = bars;
      void* args[] = { &in_p, &out_p, &wih_p, &whh_p, &bih_p, &bhh_p,
                       &h0_p, &c0_p, &hbuf_p, &bars_p, &cout_p, &wsflag };
      hipLaunchCooperativeKernel(lstm_layer, dim3(256), dim3(256), args, 0, stream);
    }
  }
}